// Round 23
// baseline (413.513 us; speedup 1.0000x reference)
//
#include <hip/hip_runtime.h>
#include <math.h>

typedef unsigned short u16;
typedef unsigned int u32;
typedef __attribute__((ext_vector_type(4))) float f32x4;
typedef __attribute__((ext_vector_type(4))) int i32x4;
typedef __attribute__((ext_vector_type(8))) short short8;
typedef __attribute__((ext_vector_type(4))) unsigned short u16x4;
typedef __attribute__((ext_vector_type(4))) __fp16 f16x4;
typedef __attribute__((ext_vector_type(2))) __fp16 f16x2;

#define DEV __device__ __forceinline__

DEV u16 f2bf(float f) {
  unsigned u = __float_as_uint(f);
  u += 0x7FFFu + ((u >> 16) & 1u);
  return (u16)(u >> 16);
}

DEV float bf2f(u16 b) { return __uint_as_float(((u32)b) << 16); }

DEV float fexp2(float x) {  // v_exp_f32 is natively 2^x
  float r;
  asm("v_exp_f32 %0, %1" : "=v"(r) : "v"(x));
  return r;
}

DEV void gload_lds16(const void* g, void* l) {
  __builtin_amdgcn_global_load_lds((const __attribute__((address_space(1))) void*)g,
                                   (__attribute__((address_space(3))) void*)l, 16, 0, 0);
}

template<int N> DEV void waitv() {
  if constexpr (N == 4)      asm volatile("s_waitcnt vmcnt(4)" ::: "memory");
  else if constexpr (N == 3) asm volatile("s_waitcnt vmcnt(3)" ::: "memory");
  else if constexpr (N == 2) asm volatile("s_waitcnt vmcnt(2)" ::: "memory");
  else                       asm volatile("s_waitcnt vmcnt(0)" ::: "memory");
}

DEV void bar() {  // raw barrier, memory-clobber only (NO sched_barrier: m141)
  asm volatile("s_barrier" ::: "memory");
}

enum { EPI_QK = 0, EPI_VT = 1, EPI_RESID_X1 = 2, EPI_GELU = 3, EPI_RESID_BF16 = 4, EPI_LOGITS = 5 };

// ---------------- weight transpose: f32 [K][Nsrc] -> bf16 [Nout][K]
__global__ void transpose_w(const float* __restrict__ in, u16* __restrict__ out,
                            int K, int Nsrc, int Nout) {
  __shared__ float tile[32][33];
  int k0 = blockIdx.x * 32, n0 = blockIdx.y * 32;
  int tx = threadIdx.x, ty = threadIdx.y;
#pragma unroll
  for (int i = 0; i < 4; ++i) {
    int k = k0 + ty + i * 8, n = n0 + tx;
    tile[ty + i * 8][tx] = (n < Nsrc) ? in[(size_t)k * Nsrc + n] : 0.0f;
  }
  __syncthreads();
#pragma unroll
  for (int i = 0; i < 4; ++i) {
    int n = n0 + ty + i * 8, k = k0 + tx;
    out[(size_t)n * K + k] = f2bf(tile[tx][ty + i * 8]);
  }
}

// ---------------- batched 1024-row transposes (z selects src/dst; z==4: w_out, Nsrc=1000)
__global__ void transpose_w5(const float* __restrict__ s0, const float* __restrict__ s1,
                             const float* __restrict__ s2, const float* __restrict__ s3,
                             const float* __restrict__ s4,
                             u16* __restrict__ d0, u16* __restrict__ d1,
                             u16* __restrict__ d2, u16* __restrict__ d3,
                             u16* __restrict__ d4) {
  __shared__ float tile[32][33];
  const float* in; u16* out; int Nsrc = 1024;
  switch (blockIdx.z) {
    case 0: in = s0; out = d0; break;
    case 1: in = s1; out = d1; break;
    case 2: in = s2; out = d2; break;
    case 3: in = s3; out = d3; break;
    default: in = s4; out = d4; Nsrc = 1000; break;
  }
  int k0 = blockIdx.x * 32, n0 = blockIdx.y * 32;
  int tx = threadIdx.x, ty = threadIdx.y;
#pragma unroll
  for (int i = 0; i < 4; ++i) {
    int k = k0 + ty + i * 8, n = n0 + tx;
    tile[ty + i * 8][tx] = (n < Nsrc) ? in[(size_t)k * Nsrc + n] : 0.0f;
  }
  __syncthreads();
#pragma unroll
  for (int i = 0; i < 4; ++i) {
    int n = n0 + ty + i * 8, k = k0 + tx;
    out[(size_t)n * 1024 + k] = f2bf(tile[tx][ty + i * 8]);
  }
}

// ---------------- f32 -> bf16 elementwise (n4 = n/4 groups)
__global__ void convert_bf16(const float* __restrict__ in, u16* __restrict__ out, int n4) {
  int i = blockIdx.x * blockDim.x + threadIdx.x;
  int stride = gridDim.x * blockDim.x;
  for (int j = i; j < n4; j += stride) {
    f32x4 v = reinterpret_cast<const f32x4*>(in)[j];
    u16x4 o;
    o[0] = f2bf(v[0]); o[1] = f2bf(v[1]); o[2] = f2bf(v[2]); o[3] = f2bf(v[3]);
    reinterpret_cast<u16x4*>(out)[j] = o;
  }
}

// ---------------- block reduce helpers (256 threads = 4 waves)
DEV float blockReduceSum(float v) {
  __shared__ float red[4];
#pragma unroll
  for (int m = 32; m >= 1; m >>= 1) v += __shfl_xor(v, m);
  __syncthreads();
  if ((threadIdx.x & 63) == 0) red[threadIdx.x >> 6] = v;
  __syncthreads();
  return red[0] + red[1] + red[2] + red[3];
}

DEV float blockReduceMax(float v) {
  __shared__ float redm[4];
#pragma unroll
  for (int m = 32; m >= 1; m >>= 1) v = fmaxf(v, __shfl_xor(v, m));
  __syncthreads();
  if ((threadIdx.x & 63) == 0) redm[threadIdx.x >> 6] = v;
  __syncthreads();
  return fmaxf(fmaxf(redm[0], redm[1]), fmaxf(redm[2], redm[3]));
}

// ---------------- LayerNorm: f32 [rows][1024] -> bf16, row per block
__global__ __launch_bounds__(256)
void layernorm_k(const float* __restrict__ x, const float* __restrict__ g,
                 const float* __restrict__ b, u16* __restrict__ out) {
  int row = blockIdx.x, t = threadIdx.x;
  const float* xr = x + (size_t)row * 1024;
  f32x4 v = *reinterpret_cast<const f32x4*>(xr + t * 4);
  float mu = blockReduceSum(v[0] + v[1] + v[2] + v[3]) * (1.0f / 1024.0f);
  f32x4 d;
  d[0] = v[0] - mu; d[1] = v[1] - mu; d[2] = v[2] - mu; d[3] = v[3] - mu;
  float var = blockReduceSum(d[0]*d[0] + d[1]*d[1] + d[2]*d[2] + d[3]*d[3]) * (1.0f / 1024.0f);
  float rstd = rsqrtf(var + 1e-5f);
  u16x4 o;
#pragma unroll
  for (int i = 0; i < 4; ++i) o[i] = f2bf(d[i] * rstd * g[t * 4 + i] + b[t * 4 + i]);
  *reinterpret_cast<u16x4*>(out + (size_t)row * 1024 + t * 4) = o;
}

// ---------------- LayerNorm, bf16 input: [rows][1024] bf16 -> bf16
__global__ __launch_bounds__(256)
void layernorm_bf16(const u16* __restrict__ x, const float* __restrict__ g,
                    const float* __restrict__ b, u16* __restrict__ out) {
  int row = blockIdx.x, t = threadIdx.x;
  const u16* xr = x + (size_t)row * 1024;
  u16x4 raw = *reinterpret_cast<const u16x4*>(xr + t * 4);
  f32x4 v;
#pragma unroll
  for (int i = 0; i < 4; ++i) v[i] = bf2f(raw[i]);
  float mu = blockReduceSum(v[0] + v[1] + v[2] + v[3]) * (1.0f / 1024.0f);
  f32x4 d;
  d[0] = v[0] - mu; d[1] = v[1] - mu; d[2] = v[2] - mu; d[3] = v[3] - mu;
  float var = blockReduceSum(d[0]*d[0] + d[1]*d[1] + d[2]*d[2] + d[3]*d[3]) * (1.0f / 1024.0f);
  float rstd = rsqrtf(var + 1e-5f);
  u16x4 o;
#pragma unroll
  for (int i = 0; i < 4; ++i) o[i] = f2bf(d[i] * rstd * g[t * 4 + i] + b[t * 4 + i]);
  *reinterpret_cast<u16x4*>(out + (size_t)row * 1024 + t * 4) = o;
}

// ---------------- final row softmax: bf16 logits [rows][1000] -> f32 probs
__global__ __launch_bounds__(256)
void softmax_rows_b(const u16* __restrict__ in, float* __restrict__ outp) {
  int row = blockIdx.x, t = threadIdx.x;
  const u16* p = in + (size_t)row * 1000;
  float* q = outp + (size_t)row * 1000;
  float v[4];
  float mx = -INFINITY;
#pragma unroll
  for (int i = 0; i < 4; ++i) {
    int c = t + i * 256;
    v[i] = (c < 1000) ? bf2f(p[c]) : -INFINITY;
    mx = fmaxf(mx, v[i]);
  }
  mx = blockReduceMax(mx);
  float s = 0.f;
#pragma unroll
  for (int i = 0; i < 4; ++i) {
    int c = t + i * 256;
    v[i] = (c < 1000) ? __expf(v[i] - mx) : 0.f;
    s += v[i];
  }
  s = blockReduceSum(s);
  float inv = 1.0f / s;
#pragma unroll
  for (int i = 0; i < 4; ++i) {
    int c = t + i * 256;
    if (c < 1000) q[c] = v[i] * inv;
  }
}

// ---------------- 8-phase pipelined bf16 MFMA GEMM, C = A @ Bt^T, XCD-swizzled.
// BM=256, BK=64, 512 thr = 8 waves (2M x 4N). BN=256: 4 phases/K-tile with
// WITHIN-TILE READ-AHEAD: bR0+bR1 both resident (loaded at P0), aR1 loaded at
// P1 -> P1/P2/P3 MFMAs consume previously-loaded regs and OVERLAP in-flight
// ds_reads (old structure serialized read->MFMA every phase via lgkmcnt).
// BN=128: 2 phases (ledger too tight for read-ahead), unchanged.
// Counted vmcnt (never 0 mid-loop), raw s_barrier. Swizzle: slot ^= (row&7).
template<int EPI, int BN>
__global__ __launch_bounds__(512, 1)
void gemm_8ph(const u16* __restrict__ A, const u16* __restrict__ Bt,
              void* __restrict__ outp, const float* __restrict__ aux0,
              const float* __restrict__ aux1, int M, int N, int K, float scale) {
  constexpr int NJ = BN / 64;             // N-frags per wave (4 or 2)
  __shared__ u16 As[2][256 * 64];
  __shared__ u16 Bs[2][BN * 64];

  const int t = threadIdx.x;
  const int lane = t & 63;
  const int w = t >> 6;
  const int wm = w >> 2, wn = w & 3;
  // XCD-aware chunked swizzle (T1): nwg % 8 == 0 for all our grids
  const int flat = blockIdx.y * gridDim.x + blockIdx.x;
  const int qch = (gridDim.x * gridDim.y) >> 3;
  const int nid = (flat & 7) * qch + (flat >> 3);
  const int bm = (nid / gridDim.x) * 256, bn = (nid % gridDim.x) * BN;
  const int l15 = lane & 15, lg = lane >> 4;
  const int nt = K >> 6;

  f32x4 acc[8][NJ] = {};
  short8 aR[2][4][2];       // double-buffered A subtiles (read-ahead)
  short8 bRr[2][2][2];      // both B halves resident (BN=128 uses [0] only)

  auto stA = [&](int buf, int kt, int q) {
    int rl = q * 64 + (t >> 3), s0 = t & 7;
    gload_lds16(A + (size_t)(bm + rl) * K + kt * 64 + (s0 ^ (rl & 7)) * 8,
                &As[buf][q * 4096 + t * 8]);
  };
  auto stB = [&](int buf, int kt, int q) {
    int rl = q * 64 + (t >> 3), s0 = t & 7;
    gload_lds16(Bt + (size_t)(bn + rl) * K + kt * 64 + (s0 ^ (rl & 7)) * 8,
                &Bs[buf][q * 4096 + t * 8]);
  };
  auto rdA = [&](int buf, int mh) {
#pragma unroll
    for (int i2 = 0; i2 < 4; ++i2) {
      int rA = wm * 128 + mh * 64 + i2 * 16 + l15;
#pragma unroll
      for (int ks = 0; ks < 2; ++ks)
        aR[mh][i2][ks] = *reinterpret_cast<const short8*>(
            &As[buf][rA * 64 + (((ks * 4 + lg) ^ (rA & 7)) * 8)]);
    }
  };
  auto rdB = [&](int buf, int nh) {
#pragma unroll
    for (int j2 = 0; j2 < 2; ++j2) {
      int rB = (BN == 256) ? (wn * 64 + nh * 32 + j2 * 16 + l15)
                           : (wn * 32 + j2 * 16 + l15);
#pragma unroll
      for (int ks = 0; ks < 2; ++ks)
        bRr[nh][j2][ks] = *reinterpret_cast<const short8*>(
            &Bs[buf][rB * 64 + (((ks * 4 + lg) ^ (rB & 7)) * 8)]);
    }
  };
  auto domfma = [&](int mh, int nh) {
    __builtin_amdgcn_s_setprio(1);
#pragma unroll
    for (int i2 = 0; i2 < 4; ++i2)
#pragma unroll
      for (int j2 = 0; j2 < 2; ++j2)
#pragma unroll
        for (int ks = 0; ks < 2; ++ks)
          acc[mh * 4 + i2][nh * 2 + j2] = __builtin_amdgcn_mfma_f32_16x16x32_bf16(
              aR[mh][i2][ks], bRr[nh][j2][ks], acc[mh * 4 + i2][nh * 2 + j2], 0, 0, 0);
    __builtin_amdgcn_s_setprio(0);
  };

  // prologue: stage tile 0 in canonical (consumption) order
  if constexpr (BN == 256) {
    stB(0, 0, 0); stB(0, 0, 1); stB(0, 0, 2); stB(0, 0, 3);
    stA(0, 0, 0); stA(0, 0, 2); stA(0, 0, 1); stA(0, 0, 3);
  } else {
    stB(0, 0, 0); stB(0, 0, 1);
    stA(0, 0, 0); stA(0, 0, 2); stA(0, 0, 1); stA(0, 0, 3);
  }

#pragma unroll 1
  for (int tt = 0; tt < nt; ++tt) {
    const int buf = tt & 1, nb = buf ^ 1;
    const bool pf = (tt + 1 < nt);
    if constexpr (BN == 256) {
      // P0: needs B(all 4 quarters: any bR spans q0-q3) + Aq0/Aq2 (= aR0);
      // oldest-6 of tile t's 8 stages -> waitv<2> leaves Aq1,Aq3 in flight.
      waitv<2>();
      bar();
      rdA(buf, 0);          // -> aR[0]
      rdB(buf, 0);          // -> bRr[0]
      rdB(buf, 1);          // -> bRr[1] (read-ahead for P1)
      if (pf) { stB(nb, tt + 1, 0); stB(nb, tt + 1, 1); }
      domfma(0, 0);         // serialized on aR0/bR0 (P0 only)
      // P1: needs Aq1/Aq3 for rdA(1); outstanding: Aq1,Aq3(t) + B0,B1(t+1)
      if (pf) waitv<2>(); else waitv<0>();
      bar();
      rdA(buf, 1);          // -> aR[1] (read-ahead for P2/P3)
      if (pf) { stB(nb, tt + 1, 2); stB(nb, tt + 1, 3); }
      domfma(0, 1);         // aR0 x bR1: regs loaded P0 -> overlaps rdA(1)
      // P2: no reads
      bar();
      if (pf) { stA(nb, tt + 1, 0); stA(nb, tt + 1, 2); }
      domfma(1, 1);         // aR1 x bR1: overlaps nothing pending -> pure MFMA
      // P3: no reads (bR0 still resident)
      bar();
      if (pf) { stA(nb, tt + 1, 1); stA(nb, tt + 1, 3); }
      domfma(1, 0);         // aR1 x bR0
    } else {
      waitv<2>();
      bar();
      rdA(buf, 0); rdB(buf, 0);
      if (pf) { stB(nb, tt + 1, 0); stB(nb, tt + 1, 1); stA(nb, tt + 1, 0); }
      domfma(0, 0);
      if (pf) waitv<3>(); else waitv<0>();
      bar();
      rdA(buf, 1);
      if (pf) { stA(nb, tt + 1, 2); stA(nb, tt + 1, 1); stA(nb, tt + 1, 3); }
      domfma(1, 0);
    }
  }

  // epilogue: C/D layout col=lane&15, row=(lane>>4)*4+reg
#pragma unroll
  for (int i = 0; i < 8; ++i)
#pragma unroll
    for (int j = 0; j < NJ; ++j)
#pragma unroll
      for (int r = 0; r < 4; ++r) {
        int row = bm + wm * 128 + i * 16 + lg * 4 + r;
        int col = bn + wn * (BN / 4) + j * 16 + l15;
        float v = acc[i][j][r];
        if constexpr (EPI == EPI_QK) {
          // q cols get SCALE*log2e folded (attn uses exp2 directly; R5-verified)
          float sc = (col < 1024) ? 0.03125f * 1.44269504088896f : 1.0f;
          ((u16*)outp)[(size_t)row * 2048 + col] = f2bf(v * sc);
        } else if constexpr (EPI == EPI_VT) {
          size_t idx = ((size_t)((row >> 11) * 16 + (col >> 6)) * 64 + (col & 63)) * 2048 + (row & 2047);
          __fp16 hv = (__fp16)v;
          ((u16*)outp)[idx] = *reinterpret_cast<u16*>(&hv);
        } else if constexpr (EPI == EPI_RESID_X1) {
          // v + bias + f32 residual -> bf16 residual stream
          ((u16*)outp)[(size_t)row * N + col] = f2bf(v + aux0[col] + aux1[(size_t)row * N + col]);
        } else if constexpr (EPI == EPI_GELU) {
          float tt2 = v + aux0[col];
          float u = tt2 * (0.7978845608f + 0.035677408f * tt2 * tt2);
          float e = fexp2(u * 2.8853900818f);
          float gl = tt2 * (1.0f - 1.0f / (1.0f + e));
          ((u16*)outp)[(size_t)row * N + col] = f2bf(gl);
        } else if constexpr (EPI == EPI_RESID_BF16) {
          // v + bias + bf16 residual (aux1 reinterpreted as u16) -> bf16
          float res = bf2f(((const u16*)aux1)[(size_t)row * N + col]);
          ((u16*)outp)[(size_t)row * N + col] = f2bf(v + aux0[col] + res);
        } else {  // EPI_LOGITS: bf16 logits (softmax reads bf16)
          if (col < 1000) ((u16*)outp)[(size_t)row * 1000 + col] = f2bf(v + aux0[col]);
        }
      }
  (void)scale; (void)aux0; (void)aux1; (void)M;
}

// ---------------- flash attention (R19-exact, measured best 89.2us): KBLK=64
// (32KB LDS -> 4 blocks/CU), QBLK=128, 4 waves x 32 q-rows (2 q-groups/wave:
// each K b128 / V b64 LDS read feeds TWO MFMAs). Shuffle-based row-sums.
// Double-buffered prefetch; no-max softmax (q carries 1/32*log2e -> exp2);
// PV via 16x16x16 f16 MFMA (S^T frag = A-frag, zero shuffles).
// QK fused buffer [8192][2048]: q cols 0-1023, k cols 1024-2047.
// Vt [64 bh][64 d][2048 n] f16 -> O [8192][1024] bf16. grid (64 bh, 16 qblk).
__global__ __launch_bounds__(256, 4)
void attn_flash(const u16* __restrict__ QKb, const u16* __restrict__ Vt,
                u16* __restrict__ Ob) {
  __shared__ u16 Ks[2][64 * 64];     // bf16 [k=64][d=64], swizzled 16B slots
  __shared__ u16 Vs[2][64 * 64];     // f16  [d=64][k=64], swizzled 16B slots
  const int t = threadIdx.x;          // 0..255
  const int lane = t & 63, w = t >> 6;   // w in 0..3
  const int l15 = lane & 15, lg = lane >> 4;
  const int bh = blockIdx.x;
  const int b = bh >> 4, h = bh & 15;
  const int qrow0 = b * 2048 + blockIdx.y * 128 + w * 32;  // wave owns 32 q-rows

  short8 qf0[2], qf1[2];  // q-group 0: rows +l15; group 1: rows +16+l15
#pragma unroll
  for (int ks = 0; ks < 2; ++ks) {
    qf0[ks] = *reinterpret_cast<const short8*>(QKb + (size_t)(qrow0 + l15) * 2048 + h * 64 + ks * 32 + lg * 8);
    qf1[ks] = *reinterpret_cast<const short8*>(QKb + (size_t)(qrow0 + 16 + l15) * 2048 + h * 64 + ks * 32 + lg * 8);
  }

  f32x4 oacc0[4] = {}, oacc1[4] = {};
  float lp0 = 0.f, lp1 = 0.f;

  // both K and V rows are 64 elems = 8 x 16B slots; same staging algebra
  const int sg8 = ((t & 7) ^ ((t >> 3) & 7)) * 8;   // pre-swizzled src slot
  const int tk8 = t * 8;

  // 256 thr x 2 chunks = 512 chunks of 16B per tile (K and V each; 8KB each).
  auto STAGE = [&](int buf, int tt) {
    int kt = tt * 64;
#pragma unroll
    for (int p = 0; p < 2; ++p) {
      int rK = p * 32 + (t >> 3);
      gload_lds16(QKb + (size_t)(b * 2048 + kt + rK) * 2048 + 1024 + h * 64 + sg8, &Ks[buf][p * 2048 + tk8]);
      int rV = p * 32 + (t >> 3);
      gload_lds16(Vt + ((size_t)bh * 64 + rV) * 2048 + kt + sg8, &Vs[buf][p * 2048 + tk8]);
    }
  };

  auto COMPUTE = [&](int buf) {
    // S^T = K Q^T: lane holds q=l15 (per group), k=cb*16+lg*4+r, cb in 0..3
    f32x4 s0[4], s1[4];
    __builtin_amdgcn_s_setprio(1);
#pragma unroll
    for (int cb = 0; cb < 4; ++cb) {
      s0[cb] = f32x4{0.f, 0.f, 0.f, 0.f};
      s1[cb] = f32x4{0.f, 0.f, 0.f, 0.f};
      int rK = cb * 16 + l15;
#pragma unroll
      for (int ks = 0; ks < 2; ++ks) {
        int sk = (lg + ks * 4) ^ (rK & 7);
        short8 kf = *reinterpret_cast<const short8*>(&Ks[buf][rK * 64 + sk * 8]);
        s0[cb] = __builtin_amdgcn_mfma_f32_16x16x32_bf16(kf, qf0[ks], s0[cb], 0, 0, 0);
        s1[cb] = __builtin_amdgcn_mfma_f32_16x16x32_bf16(kf, qf1[ks], s1[cb], 0, 0, 0);
      }
    }
    __builtin_amdgcn_s_setprio(0);

    const char* vbase = (const char*)&Vs[buf][0];
#pragma unroll
    for (int cb = 0; cb < 4; ++cb) {
      float a0 = fexp2(s0[cb][0]), a1 = fexp2(s0[cb][1]);
      float a2 = fexp2(s0[cb][2]), a3 = fexp2(s0[cb][3]);
      lp0 += (a0 + a1) + (a2 + a3);
      f16x2 plo0 = __builtin_amdgcn_cvt_pkrtz(a0, a1);
      f16x2 phi0 = __builtin_amdgcn_cvt_pkrtz(a2, a3);
      f16x4 pf0;
      pf0[0] = plo0[0]; pf0[1] = plo0[1]; pf0[2] = phi0[0]; pf0[3] = phi0[1];
      float c0 = fexp2(s1[cb][0]), c1 = fexp2(s1[cb][1]);
      float c2 = fexp2(s1[cb][2]), c3 = fexp2(s1[cb][3]);
      lp1 += (c0 + c1) + (c2 + c3);
      f16x2 plo1 = __builtin_amdgcn_cvt_pkrtz(c0, c1);
      f16x2 phi1 = __builtin_amdgcn_cvt_pkrtz(c2, c3);
      f16x4 pf1;
      pf1[0] = plo1[0]; pf1[1] = plo1[1]; pf1[2] = phi1[0]; pf1[3] = phi1[1];
      // P fragment already in x16 A-layout: lane holds P[q=l15][k=16cb+4lg+j]
      __builtin_amdgcn_s_setprio(1);
#pragma unroll
      for (int db = 0; db < 4; ++db) {
        int d = db * 16 + l15;
        // V^T[d][k] b64: row stride 128B (8 slots); logical slot 2cb+(lg>>1)
        int boff = d * 128 + ((((2 * cb + (lg >> 1)) ^ (d & 7)) << 4) | ((lg & 1) << 3));
        f16x4 vf = *reinterpret_cast<const f16x4*>(vbase + boff);
        oacc0[db] = __builtin_amdgcn_mfma_f32_16x16x16f16(pf0, vf, oacc0[db], 0, 0, 0);
        oacc1[db] = __builtin_amdgcn_mfma_f32_16x16x16f16(pf1, vf, oacc1[db], 0, 0, 0);
      }
      __builtin_amdgcn_s_setprio(0);
    }
  };

  STAGE(0, 0);
  __syncthreads();  // drains vmcnt(0): tile 0 staged
#pragma unroll 1
  for (int i = 0; i < 16; ++i) {
    STAGE(1, 2 * i + 1);   // prefetch overlaps compute below
    COMPUTE(0);
    __syncthreads();       // drains prefetch; buf1 ready, buf0 free
    if (i < 15) STAGE(0, 2 * i + 2);
    COMPUTE(1);
    __syncthreads();
  }

  // row-sum reduce + O write, group 0 (rows qrow0 + lg*4+r)
  lp0 += __shfl_xor(lp0, 16);
  lp0 += __shfl_xor(lp0, 32);
  float inv0 = 1.0f / lp0;
  float invr0[4];
#pragma unroll
  for (int r = 0; r < 4; ++r) invr0[r] = __shfl(inv0, lg * 4 + r);
#pragma unroll
  for (int db = 0; db < 4; ++db)
#pragma unroll
    for (int r = 0; r < 4; ++r) {
      int row = qrow0 + lg * 4 + r;
      int col = h * 64 + db * 16 + l15;
      Ob[(size_t)row * 1024 + col] = f2bf(oacc0[db][r] * invr0[r]);
    }
  // group 1 (rows qrow0 + 16 + lg*4+r)
  lp1 += __shfl_xor(lp1, 16);
  lp1 += __shfl_xor(lp1, 32);
  float inv1 = 1.0f / lp1;
  float invr1[4];
#pragma unroll
  for (int r = 0; r < 4; ++r) invr1[r] = __shfl(inv1, lg * 4 + r);
#pragma unroll
  for (int db = 0; db < 4; ++db)
#pragma unroll
    for (int r = 0; r < 4; ++r) {
      int row = qrow0 + 16 + lg * 4 + r;
      int col = h * 64 + db * 16 + l15;
      Ob[(size_t)row * 1024 + col] = f2bf(oacc1[db][r] * invr1[r]);
    }
}

extern "C" void kernel_launch(void* const* d_in, const int* in_sizes, int n_in,
                              void* d_out, int out_size, void* d_ws, size_t ws_size,
                              hipStream_t stream) {
  (void)in_sizes; (void)n_in; (void)out_size; (void)ws_size;
  const float* x     = (const float*)d_in[0];
  const float* value = (const float*)d_in[1];
  const float* wq    = (const float*)d_in[2];
  const float* wk    = (const float*)d_in[3];
  const float* wv    = (const float*)d_in[4];
  const float* w_ap  = (const float*)d_in[5];
  const float* b_ap  = (const float*)d_in[6];
  const float* g1    = (const float*)d_in[7];
  const float* be1   = (const float*)d_in[8];
  const float* g2    = (const float*)d_in[9];
  const float* be2   = (const float*)d_in[10];
  const float* w1    = (const float*)d_in[11];
  const float* b1    = (const float*)d_in[12];
  const float* w2    = (const float*)d_in[13];
  const float* b2    = (const float*)d_in[14];
  const float* w_out = (const float*)d_in[15];
  const float* b_out = (const float*)d_in[16];

  // workspace arena (aliased)
  char* ws = (char*)d_ws;
  u16* wqT   = (u16*)(ws + 0x0000000);  // wq^T then wk^T contiguous -> [2048][1024]
  u16* wkT   = (u16*)(ws + 0x0200000);
  u16* wvT   = (u16*)(ws + 0x0400000);
  u16* wapT  = (u16*)(ws + 0x0600000);
  u16* woutT = (u16*)(ws + 0x0800000);  // padded to [1024][1024]
  u16* w1T   = (u16*)(ws + 0x0A00000);
  u16* w2T   = (u16*)(ws + 0x1200000);
  u16* xn    = (u16*)(ws + 0x1A00000);  // later reused as xn2
  u16* valb  = (u16*)(ws + 0x2A00000);  // later reused as start of h
  u16* qkb   = (u16*)(ws + 0x3A00000);  // fused [8192][2048] bf16 (32 MB)
  u16* vT    = (u16*)(ws + 0x5A00000);  // f16
  u16* ob    = (u16*)(ws + 0x6A00000);  // later reused as x2b
  u16* x1b   = (u16*)(ws + 0x7A00000);  // bf16 residual stream (16 MB)
  u16* logb  = (u16*)(ws + 0x8A00000);  // bf16 logits [8192][1000]
  u16* hb    = valb;
  u16* xn2   = xn;
  u16* x2b   = ob;

  dim3 tb(32, 8);
  transpose_w5<<<dim3(32, 32, 5), tb, 0, stream>>>(wq, wk, wv, w_ap, w_out,
                                                   wqT, wkT, wvT, wapT, woutT);
  transpose_w<<<dim3(32, 128), tb, 0, stream>>>(w1, w1T, 1024, 4096, 4096);
  transpose_w<<<dim3(128, 32), tb, 0, stream>>>(w2, w2T, 4096, 1024, 1024);

  convert_bf16<<<2048, 256, 0, stream>>>(value, valb, 2097152);
  layernorm_k<<<8192, 256, 0, stream>>>(x, g1, be1, xn);

  // fused q|k projection (q cols scaled 1/32*log2e in epilogue)
  gemm_8ph<EPI_QK, 256><<<dim3(8, 32),  512, 0, stream>>>(xn,   wqT, qkb, nullptr, nullptr, 8192, 2048, 1024, 1.0f);
  gemm_8ph<EPI_VT, 128><<<dim3(8, 32),  512, 0, stream>>>(valb, wvT, vT,  nullptr, nullptr, 8192, 1024, 1024, 1.0f);

  attn_flash<<<dim3(64, 16), 256, 0, stream>>>(qkb, vT, ob);

  gemm_8ph<EPI_RESID_X1, 128><<<dim3(8, 32),  512, 0, stream>>>(ob,  wapT, x1b, b_ap, x, 8192, 1024, 1024, 1.0f);
  layernorm_bf16<<<8192, 256, 0, stream>>>(x1b, g2, be2, xn2);
  gemm_8ph<EPI_GELU, 256>     <<<dim3(16, 32), 512, 0, stream>>>(xn2, w1T, hb, b1, nullptr, 8192, 4096, 1024, 1.0f);
  gemm_8ph<EPI_RESID_BF16, 128><<<dim3(8, 32), 512, 0, stream>>>(hb,  w2T, x2b, b2, (const float*)x1b, 8192, 1024, 4096, 1.0f);
  gemm_8ph<EPI_LOGITS, 128>   <<<dim3(8, 32),  512, 0, stream>>>(x2b, woutT, logb, b_out, nullptr, 8192, 1024, 1024, 1.0f);
  softmax_rows_b<<<8192, 256, 0, stream>>>(logb, (float*)d_out);
}

// Round 24
// 412.043 us; speedup vs baseline: 1.0036x; 1.0036x over previous
//
#include <hip/hip_runtime.h>
#include <math.h>

typedef unsigned short u16;
typedef unsigned int u32;
typedef __attribute__((ext_vector_type(4))) float f32x4;
typedef __attribute__((ext_vector_type(4))) int i32x4;
typedef __attribute__((ext_vector_type(8))) short short8;
typedef __attribute__((ext_vector_type(4))) unsigned short u16x4;
typedef __attribute__((ext_vector_type(4))) __fp16 f16x4;
typedef __attribute__((ext_vector_type(2))) __fp16 f16x2;

#define DEV __device__ __forceinline__

DEV u16 f2bf(float f) {
  unsigned u = __float_as_uint(f);
  u += 0x7FFFu + ((u >> 16) & 1u);
  return (u16)(u >> 16);
}

DEV float bf2f(u16 b) { return __uint_as_float(((u32)b) << 16); }

DEV float fexp2(float x) {  // v_exp_f32 is natively 2^x
  float r;
  asm("v_exp_f32 %0, %1" : "=v"(r) : "v"(x));
  return r;
}

DEV void gload_lds16(const void* g, void* l) {
  __builtin_amdgcn_global_load_lds((const __attribute__((address_space(1))) void*)g,
                                   (__attribute__((address_space(3))) void*)l, 16, 0, 0);
}

template<int N> DEV void waitv() {
  if constexpr (N == 4)      asm volatile("s_waitcnt vmcnt(4)" ::: "memory");
  else if constexpr (N == 3) asm volatile("s_waitcnt vmcnt(3)" ::: "memory");
  else if constexpr (N == 2) asm volatile("s_waitcnt vmcnt(2)" ::: "memory");
  else                       asm volatile("s_waitcnt vmcnt(0)" ::: "memory");
}

DEV void bar() {  // raw barrier, memory-clobber only (NO sched_barrier: m141)
  asm volatile("s_barrier" ::: "memory");
}

enum { EPI_QK = 0, EPI_VT = 1, EPI_RESID_X1 = 2, EPI_GELU = 3, EPI_RESID_BF16 = 4, EPI_LOGITS = 5 };

// ---------------- weight transpose: f32 [K][Nsrc] -> bf16 [Nout][K]
__global__ void transpose_w(const float* __restrict__ in, u16* __restrict__ out,
                            int K, int Nsrc, int Nout) {
  __shared__ float tile[32][33];
  int k0 = blockIdx.x * 32, n0 = blockIdx.y * 32;
  int tx = threadIdx.x, ty = threadIdx.y;
#pragma unroll
  for (int i = 0; i < 4; ++i) {
    int k = k0 + ty + i * 8, n = n0 + tx;
    tile[ty + i * 8][tx] = (n < Nsrc) ? in[(size_t)k * Nsrc + n] : 0.0f;
  }
  __syncthreads();
#pragma unroll
  for (int i = 0; i < 4; ++i) {
    int n = n0 + ty + i * 8, k = k0 + tx;
    out[(size_t)n * K + k] = f2bf(tile[tx][ty + i * 8]);
  }
}

// ---------------- batched 1024-row transposes (z selects src/dst; z==4: w_out, Nsrc=1000)
__global__ void transpose_w5(const float* __restrict__ s0, const float* __restrict__ s1,
                             const float* __restrict__ s2, const float* __restrict__ s3,
                             const float* __restrict__ s4,
                             u16* __restrict__ d0, u16* __restrict__ d1,
                             u16* __restrict__ d2, u16* __restrict__ d3,
                             u16* __restrict__ d4) {
  __shared__ float tile[32][33];
  const float* in; u16* out; int Nsrc = 1024;
  switch (blockIdx.z) {
    case 0: in = s0; out = d0; break;
    case 1: in = s1; out = d1; break;
    case 2: in = s2; out = d2; break;
    case 3: in = s3; out = d3; break;
    default: in = s4; out = d4; Nsrc = 1000; break;
  }
  int k0 = blockIdx.x * 32, n0 = blockIdx.y * 32;
  int tx = threadIdx.x, ty = threadIdx.y;
#pragma unroll
  for (int i = 0; i < 4; ++i) {
    int k = k0 + ty + i * 8, n = n0 + tx;
    tile[ty + i * 8][tx] = (n < Nsrc) ? in[(size_t)k * Nsrc + n] : 0.0f;
  }
  __syncthreads();
#pragma unroll
  for (int i = 0; i < 4; ++i) {
    int n = n0 + ty + i * 8, k = k0 + tx;
    out[(size_t)n * 1024 + k] = f2bf(tile[tx][ty + i * 8]);
  }
}

// ---------------- f32 -> bf16 elementwise (n4 = n/4 groups)
__global__ void convert_bf16(const float* __restrict__ in, u16* __restrict__ out, int n4) {
  int i = blockIdx.x * blockDim.x + threadIdx.x;
  int stride = gridDim.x * blockDim.x;
  for (int j = i; j < n4; j += stride) {
    f32x4 v = reinterpret_cast<const f32x4*>(in)[j];
    u16x4 o;
    o[0] = f2bf(v[0]); o[1] = f2bf(v[1]); o[2] = f2bf(v[2]); o[3] = f2bf(v[3]);
    reinterpret_cast<u16x4*>(out)[j] = o;
  }
}

// ---------------- block reduce helpers (256 threads = 4 waves)
DEV float blockReduceSum(float v) {
  __shared__ float red[4];
#pragma unroll
  for (int m = 32; m >= 1; m >>= 1) v += __shfl_xor(v, m);
  __syncthreads();
  if ((threadIdx.x & 63) == 0) red[threadIdx.x >> 6] = v;
  __syncthreads();
  return red[0] + red[1] + red[2] + red[3];
}

DEV float blockReduceMax(float v) {
  __shared__ float redm[4];
#pragma unroll
  for (int m = 32; m >= 1; m >>= 1) v = fmaxf(v, __shfl_xor(v, m));
  __syncthreads();
  if ((threadIdx.x & 63) == 0) redm[threadIdx.x >> 6] = v;
  __syncthreads();
  return fmaxf(fmaxf(redm[0], redm[1]), fmaxf(redm[2], redm[3]));
}

// ---------------- LayerNorm: f32 [rows][1024] -> bf16, row per block
__global__ __launch_bounds__(256)
void layernorm_k(const float* __restrict__ x, const float* __restrict__ g,
                 const float* __restrict__ b, u16* __restrict__ out) {
  int row = blockIdx.x, t = threadIdx.x;
  const float* xr = x + (size_t)row * 1024;
  f32x4 v = *reinterpret_cast<const f32x4*>(xr + t * 4);
  float mu = blockReduceSum(v[0] + v[1] + v[2] + v[3]) * (1.0f / 1024.0f);
  f32x4 d;
  d[0] = v[0] - mu; d[1] = v[1] - mu; d[2] = v[2] - mu; d[3] = v[3] - mu;
  float var = blockReduceSum(d[0]*d[0] + d[1]*d[1] + d[2]*d[2] + d[3]*d[3]) * (1.0f / 1024.0f);
  float rstd = rsqrtf(var + 1e-5f);
  u16x4 o;
#pragma unroll
  for (int i = 0; i < 4; ++i) o[i] = f2bf(d[i] * rstd * g[t * 4 + i] + b[t * 4 + i]);
  *reinterpret_cast<u16x4*>(out + (size_t)row * 1024 + t * 4) = o;
}

// ---------------- LayerNorm, bf16 input: [rows][1024] bf16 -> bf16
__global__ __launch_bounds__(256)
void layernorm_bf16(const u16* __restrict__ x, const float* __restrict__ g,
                    const float* __restrict__ b, u16* __restrict__ out) {
  int row = blockIdx.x, t = threadIdx.x;
  const u16* xr = x + (size_t)row * 1024;
  u16x4 raw = *reinterpret_cast<const u16x4*>(xr + t * 4);
  f32x4 v;
#pragma unroll
  for (int i = 0; i < 4; ++i) v[i] = bf2f(raw[i]);
  float mu = blockReduceSum(v[0] + v[1] + v[2] + v[3]) * (1.0f / 1024.0f);
  f32x4 d;
  d[0] = v[0] - mu; d[1] = v[1] - mu; d[2] = v[2] - mu; d[3] = v[3] - mu;
  float var = blockReduceSum(d[0]*d[0] + d[1]*d[1] + d[2]*d[2] + d[3]*d[3]) * (1.0f / 1024.0f);
  float rstd = rsqrtf(var + 1e-5f);
  u16x4 o;
#pragma unroll
  for (int i = 0; i < 4; ++i) o[i] = f2bf(d[i] * rstd * g[t * 4 + i] + b[t * 4 + i]);
  *reinterpret_cast<u16x4*>(out + (size_t)row * 1024 + t * 4) = o;
}

// ---------------- final row softmax: bf16 logits [rows][1000] -> f32 probs
__global__ __launch_bounds__(256)
void softmax_rows_b(const u16* __restrict__ in, float* __restrict__ outp) {
  int row = blockIdx.x, t = threadIdx.x;
  const u16* p = in + (size_t)row * 1000;
  float* q = outp + (size_t)row * 1000;
  float v[4];
  float mx = -INFINITY;
#pragma unroll
  for (int i = 0; i < 4; ++i) {
    int c = t + i * 256;
    v[i] = (c < 1000) ? bf2f(p[c]) : -INFINITY;
    mx = fmaxf(mx, v[i]);
  }
  mx = blockReduceMax(mx);
  float s = 0.f;
#pragma unroll
  for (int i = 0; i < 4; ++i) {
    int c = t + i * 256;
    v[i] = (c < 1000) ? __expf(v[i] - mx) : 0.f;
    s += v[i];
  }
  s = blockReduceSum(s);
  float inv = 1.0f / s;
#pragma unroll
  for (int i = 0; i < 4; ++i) {
    int c = t + i * 256;
    if (c < 1000) q[c] = v[i] * inv;
  }
}

// ---------------- 8-phase pipelined bf16 MFMA GEMM, C = A @ Bt^T, XCD-swizzled.
// BM=256, BK=64, 512 thr = 8 waves (2M x 4N). BN=256: 4 phases/K-tile; BN=128: 2.
// Counted vmcnt (never 0 mid-loop), raw s_barrier. Swizzle: slot ^= (row&7).
// (R23 read-ahead variant A/B'd neutral-negative; this is the R22-measured-best.)
template<int EPI, int BN>
__global__ __launch_bounds__(512, 1)
void gemm_8ph(const u16* __restrict__ A, const u16* __restrict__ Bt,
              void* __restrict__ outp, const float* __restrict__ aux0,
              const float* __restrict__ aux1, int M, int N, int K, float scale) {
  constexpr int NJ = BN / 64;             // N-frags per wave (4 or 2)
  __shared__ u16 As[2][256 * 64];
  __shared__ u16 Bs[2][BN * 64];

  const int t = threadIdx.x;
  const int lane = t & 63;
  const int w = t >> 6;
  const int wm = w >> 2, wn = w & 3;
  // XCD-aware chunked swizzle (T1): nwg % 8 == 0 for all our grids
  const int flat = blockIdx.y * gridDim.x + blockIdx.x;
  const int qch = (gridDim.x * gridDim.y) >> 3;
  const int nid = (flat & 7) * qch + (flat >> 3);
  const int bm = (nid / gridDim.x) * 256, bn = (nid % gridDim.x) * BN;
  const int l15 = lane & 15, lg = lane >> 4;
  const int nt = K >> 6;

  f32x4 acc[8][NJ] = {};
  short8 aR[4][2], bR[2][2];

  auto stA = [&](int buf, int kt, int q) {
    int rl = q * 64 + (t >> 3), s0 = t & 7;
    gload_lds16(A + (size_t)(bm + rl) * K + kt * 64 + (s0 ^ (rl & 7)) * 8,
                &As[buf][q * 4096 + t * 8]);
  };
  auto stB = [&](int buf, int kt, int q) {
    int rl = q * 64 + (t >> 3), s0 = t & 7;
    gload_lds16(Bt + (size_t)(bn + rl) * K + kt * 64 + (s0 ^ (rl & 7)) * 8,
                &Bs[buf][q * 4096 + t * 8]);
  };
  auto rdA = [&](int buf, int mh) {
#pragma unroll
    for (int i2 = 0; i2 < 4; ++i2) {
      int rA = wm * 128 + mh * 64 + i2 * 16 + l15;
#pragma unroll
      for (int ks = 0; ks < 2; ++ks)
        aR[i2][ks] = *reinterpret_cast<const short8*>(
            &As[buf][rA * 64 + (((ks * 4 + lg) ^ (rA & 7)) * 8)]);
    }
  };
  auto rdB = [&](int buf, int nh) {
#pragma unroll
    for (int j2 = 0; j2 < 2; ++j2) {
      int rB = (BN == 256) ? (wn * 64 + nh * 32 + j2 * 16 + l15)
                           : (wn * 32 + j2 * 16 + l15);
#pragma unroll
      for (int ks = 0; ks < 2; ++ks)
        bR[j2][ks] = *reinterpret_cast<const short8*>(
            &Bs[buf][rB * 64 + (((ks * 4 + lg) ^ (rB & 7)) * 8)]);
    }
  };
  auto domfma = [&](int mh, int nh) {
    __builtin_amdgcn_s_setprio(1);
#pragma unroll
    for (int i2 = 0; i2 < 4; ++i2)
#pragma unroll
      for (int j2 = 0; j2 < 2; ++j2)
#pragma unroll
        for (int ks = 0; ks < 2; ++ks)
          acc[mh * 4 + i2][nh * 2 + j2] = __builtin_amdgcn_mfma_f32_16x16x32_bf16(
              aR[i2][ks], bR[j2][ks], acc[mh * 4 + i2][nh * 2 + j2], 0, 0, 0);
    __builtin_amdgcn_s_setprio(0);
  };

  // prologue: stage tile 0 in canonical (consumption) order
  if constexpr (BN == 256) {
    stB(0, 0, 0); stB(0, 0, 1); stB(0, 0, 2); stB(0, 0, 3);
    stA(0, 0, 0); stA(0, 0, 2); stA(0, 0, 1); stA(0, 0, 3);
  } else {
    stB(0, 0, 0); stB(0, 0, 1);
    stA(0, 0, 0); stA(0, 0, 2); stA(0, 0, 1); stA(0, 0, 3);
  }

#pragma unroll 1
  for (int tt = 0; tt < nt; ++tt) {
    const int buf = tt & 1, nb = buf ^ 1;
    const bool pf = (tt + 1 < nt);
    if constexpr (BN == 256) {
      waitv<2>();
      bar();
      rdA(buf, 0); rdB(buf, 0);
      if (pf) { stB(nb, tt + 1, 0); stB(nb, tt + 1, 1); }
      domfma(0, 0);
      bar();
      rdB(buf, 1);
      if (pf) { stB(nb, tt + 1, 2); stB(nb, tt + 1, 3); }
      domfma(0, 1);
      if (pf) waitv<4>(); else waitv<0>();
      bar();
      rdA(buf, 1);
      if (pf) { stA(nb, tt + 1, 0); stA(nb, tt + 1, 2); }
      domfma(1, 1);
      bar();
      rdB(buf, 0);
      if (pf) { stA(nb, tt + 1, 1); stA(nb, tt + 1, 3); }
      domfma(1, 0);
    } else {
      waitv<2>();
      bar();
      rdA(buf, 0); rdB(buf, 0);
      if (pf) { stB(nb, tt + 1, 0); stB(nb, tt + 1, 1); stA(nb, tt + 1, 0); }
      domfma(0, 0);
      if (pf) waitv<3>(); else waitv<0>();
      bar();
      rdA(buf, 1);
      if (pf) { stA(nb, tt + 1, 2); stA(nb, tt + 1, 1); stA(nb, tt + 1, 3); }
      domfma(1, 0);
    }
  }

  // epilogue: C/D layout col=lane&15, row=(lane>>4)*4+reg
#pragma unroll
  for (int i = 0; i < 8; ++i)
#pragma unroll
    for (int j = 0; j < NJ; ++j)
#pragma unroll
      for (int r = 0; r < 4; ++r) {
        int row = bm + wm * 128 + i * 16 + lg * 4 + r;
        int col = bn + wn * (BN / 4) + j * 16 + l15;
        float v = acc[i][j][r];
        if constexpr (EPI == EPI_QK) {
          // q cols get SCALE*log2e folded (attn uses exp2 directly; R5-verified)
          float sc = (col < 1024) ? 0.03125f * 1.44269504088896f : 1.0f;
          ((u16*)outp)[(size_t)row * 2048 + col] = f2bf(v * sc);
        } else if constexpr (EPI == EPI_VT) {
          size_t idx = ((size_t)((row >> 11) * 16 + (col >> 6)) * 64 + (col & 63)) * 2048 + (row & 2047);
          __fp16 hv = (__fp16)v;
          ((u16*)outp)[idx] = *reinterpret_cast<u16*>(&hv);
        } else if constexpr (EPI == EPI_RESID_X1) {
          // v + bias + f32 residual -> bf16 residual stream
          ((u16*)outp)[(size_t)row * N + col] = f2bf(v + aux0[col] + aux1[(size_t)row * N + col]);
        } else if constexpr (EPI == EPI_GELU) {
          float tt2 = v + aux0[col];
          float u = tt2 * (0.7978845608f + 0.035677408f * tt2 * tt2);
          float e = fexp2(u * 2.8853900818f);
          float gl = tt2 * (1.0f - 1.0f / (1.0f + e));
          ((u16*)outp)[(size_t)row * N + col] = f2bf(gl);
        } else if constexpr (EPI == EPI_RESID_BF16) {
          // v + bias + bf16 residual (aux1 reinterpreted as u16) -> bf16
          float res = bf2f(((const u16*)aux1)[(size_t)row * N + col]);
          ((u16*)outp)[(size_t)row * N + col] = f2bf(v + aux0[col] + res);
        } else {  // EPI_LOGITS: bf16 logits (softmax reads bf16)
          if (col < 1000) ((u16*)outp)[(size_t)row * 1000 + col] = f2bf(v + aux0[col]);
        }
      }
  (void)scale; (void)aux0; (void)aux1; (void)M;
}

// ---------------- flash attention (R19-exact, measured best ~89us): KBLK=64
// (32KB LDS -> 4 blocks/CU), QBLK=128, 4 waves x 32 q-rows (2 q-groups/wave:
// each K b128 / V b64 LDS read feeds TWO MFMAs). Shuffle-based row-sums.
// Double-buffered prefetch; no-max softmax (q carries 1/32*log2e -> exp2);
// PV via 16x16x16 f16 MFMA (S^T frag = A-frag, zero shuffles).
// QK fused buffer [8192][2048]: q cols 0-1023, k cols 1024-2047.
// Vt [64 bh][64 d][2048 n] f16 -> O [8192][1024] bf16. grid (64 bh, 16 qblk).
__global__ __launch_bounds__(256, 4)
void attn_flash(const u16* __restrict__ QKb, const u16* __restrict__ Vt,
                u16* __restrict__ Ob) {
  __shared__ u16 Ks[2][64 * 64];     // bf16 [k=64][d=64], swizzled 16B slots
  __shared__ u16 Vs[2][64 * 64];     // f16  [d=64][k=64], swizzled 16B slots
  const int t = threadIdx.x;          // 0..255
  const int lane = t & 63, w = t >> 6;   // w in 0..3
  const int l15 = lane & 15, lg = lane >> 4;
  const int bh = blockIdx.x;
  const int b = bh >> 4, h = bh & 15;
  const int qrow0 = b * 2048 + blockIdx.y * 128 + w * 32;  // wave owns 32 q-rows

  short8 qf0[2], qf1[2];  // q-group 0: rows +l15; group 1: rows +16+l15
#pragma unroll
  for (int ks = 0; ks < 2; ++ks) {
    qf0[ks] = *reinterpret_cast<const short8*>(QKb + (size_t)(qrow0 + l15) * 2048 + h * 64 + ks * 32 + lg * 8);
    qf1[ks] = *reinterpret_cast<const short8*>(QKb + (size_t)(qrow0 + 16 + l15) * 2048 + h * 64 + ks * 32 + lg * 8);
  }

  f32x4 oacc0[4] = {}, oacc1[4] = {};
  float lp0 = 0.f, lp1 = 0.f;

  // both K and V rows are 64 elems = 8 x 16B slots; same staging algebra
  const int sg8 = ((t & 7) ^ ((t >> 3) & 7)) * 8;   // pre-swizzled src slot
  const int tk8 = t * 8;

  // 256 thr x 2 chunks = 512 chunks of 16B per tile (K and V each; 8KB each).
  auto STAGE = [&](int buf, int tt) {
    int kt = tt * 64;
#pragma unroll
    for (int p = 0; p < 2; ++p) {
      int rK = p * 32 + (t >> 3);
      gload_lds16(QKb + (size_t)(b * 2048 + kt + rK) * 2048 + 1024 + h * 64 + sg8, &Ks[buf][p * 2048 + tk8]);
      int rV = p * 32 + (t >> 3);
      gload_lds16(Vt + ((size_t)bh * 64 + rV) * 2048 + kt + sg8, &Vs[buf][p * 2048 + tk8]);
    }
  };

  auto COMPUTE = [&](int buf) {
    // S^T = K Q^T: lane holds q=l15 (per group), k=cb*16+lg*4+r, cb in 0..3
    f32x4 s0[4], s1[4];
    __builtin_amdgcn_s_setprio(1);
#pragma unroll
    for (int cb = 0; cb < 4; ++cb) {
      s0[cb] = f32x4{0.f, 0.f, 0.f, 0.f};
      s1[cb] = f32x4{0.f, 0.f, 0.f, 0.f};
      int rK = cb * 16 + l15;
#pragma unroll
      for (int ks = 0; ks < 2; ++ks) {
        int sk = (lg + ks * 4) ^ (rK & 7);
        short8 kf = *reinterpret_cast<const short8*>(&Ks[buf][rK * 64 + sk * 8]);
        s0[cb] = __builtin_amdgcn_mfma_f32_16x16x32_bf16(kf, qf0[ks], s0[cb], 0, 0, 0);
        s1[cb] = __builtin_amdgcn_mfma_f32_16x16x32_bf16(kf, qf1[ks], s1[cb], 0, 0, 0);
      }
    }
    __builtin_amdgcn_s_setprio(0);

    const char* vbase = (const char*)&Vs[buf][0];
#pragma unroll
    for (int cb = 0; cb < 4; ++cb) {
      float a0 = fexp2(s0[cb][0]), a1 = fexp2(s0[cb][1]);
      float a2 = fexp2(s0[cb][2]), a3 = fexp2(s0[cb][3]);
      lp0 += (a0 + a1) + (a2 + a3);
      f16x2 plo0 = __builtin_amdgcn_cvt_pkrtz(a0, a1);
      f16x2 phi0 = __builtin_amdgcn_cvt_pkrtz(a2, a3);
      f16x4 pf0;
      pf0[0] = plo0[0]; pf0[1] = plo0[1]; pf0[2] = phi0[0]; pf0[3] = phi0[1];
      float c0 = fexp2(s1[cb][0]), c1 = fexp2(s1[cb][1]);
      float c2 = fexp2(s1[cb][2]), c3 = fexp2(s1[cb][3]);
      lp1 += (c0 + c1) + (c2 + c3);
      f16x2 plo1 = __builtin_amdgcn_cvt_pkrtz(c0, c1);
      f16x2 phi1 = __builtin_amdgcn_cvt_pkrtz(c2, c3);
      f16x4 pf1;
      pf1[0] = plo1[0]; pf1[1] = plo1[1]; pf1[2] = phi1[0]; pf1[3] = phi1[1];
      // P fragment already in x16 A-layout: lane holds P[q=l15][k=16cb+4lg+j]
      __builtin_amdgcn_s_setprio(1);
#pragma unroll
      for (int db = 0; db < 4; ++db) {
        int d = db * 16 + l15;
        // V^T[d][k] b64: row stride 128B (8 slots); logical slot 2cb+(lg>>1)
        int boff = d * 128 + ((((2 * cb + (lg >> 1)) ^ (d & 7)) << 4) | ((lg & 1) << 3));
        f16x4 vf = *reinterpret_cast<const f16x4*>(vbase + boff);
        oacc0[db] = __builtin_amdgcn_mfma_f32_16x16x16f16(pf0, vf, oacc0[db], 0, 0, 0);
        oacc1[db] = __builtin_amdgcn_mfma_f32_16x16x16f16(pf1, vf, oacc1[db], 0, 0, 0);
      }
      __builtin_amdgcn_s_setprio(0);
    }
  };

  STAGE(0, 0);
  __syncthreads();  // drains vmcnt(0): tile 0 staged
#pragma unroll 1
  for (int i = 0; i < 16; ++i) {
    STAGE(1, 2 * i + 1);   // prefetch overlaps compute below
    COMPUTE(0);
    __syncthreads();       // drains prefetch; buf1 ready, buf0 free
    if (i < 15) STAGE(0, 2 * i + 2);
    COMPUTE(1);
    __syncthreads();
  }

  // row-sum reduce + O write, group 0 (rows qrow0 + lg*4+r)
  lp0 += __shfl_xor(lp0, 16);
  lp0 += __shfl_xor(lp0, 32);
  float inv0 = 1.0f / lp0;
  float invr0[4];
#pragma unroll
  for (int r = 0; r < 4; ++r) invr0[r] = __shfl(inv0, lg * 4 + r);
#pragma unroll
  for (int db = 0; db < 4; ++db)
#pragma unroll
    for (int r = 0; r < 4; ++r) {
      int row = qrow0 + lg * 4 + r;
      int col = h * 64 + db * 16 + l15;
      Ob[(size_t)row * 1024 + col] = f2bf(oacc0[db][r] * invr0[r]);
    }
  // group 1 (rows qrow0 + 16 + lg*4+r)
  lp1 += __shfl_xor(lp1, 16);
  lp1 += __shfl_xor(lp1, 32);
  float inv1 = 1.0f / lp1;
  float invr1[4];
#pragma unroll
  for (int r = 0; r < 4; ++r) invr1[r] = __shfl(inv1, lg * 4 + r);
#pragma unroll
  for (int db = 0; db < 4; ++db)
#pragma unroll
    for (int r = 0; r < 4; ++r) {
      int row = qrow0 + 16 + lg * 4 + r;
      int col = h * 64 + db * 16 + l15;
      Ob[(size_t)row * 1024 + col] = f2bf(oacc1[db][r] * invr1[r]);
    }
}

extern "C" void kernel_launch(void* const* d_in, const int* in_sizes, int n_in,
                              void* d_out, int out_size, void* d_ws, size_t ws_size,
                              hipStream_t stream) {
  (void)in_sizes; (void)n_in; (void)out_size; (void)ws_size;
  const float* x     = (const float*)d_in[0];
  const float* value = (const float*)d_in[1];
  const float* wq    = (const float*)d_in[2];
  const float* wk    = (const float*)d_in[3];
  const float* wv    = (const float*)d_in[4];
  const float* w_ap  = (const float*)d_in[5];
  const float* b_ap  = (const float*)d_in[6];
  const float* g1    = (const float*)d_in[7];
  const float* be1   = (const float*)d_in[8];
  const float* g2    = (const float*)d_in[9];
  const float* be2   = (const float*)d_in[10];
  const float* w1    = (const float*)d_in[11];
  const float* b1    = (const float*)d_in[12];
  const float* w2    = (const float*)d_in[13];
  const float* b2    = (const float*)d_in[14];
  const float* w_out = (const float*)d_in[15];
  const float* b_out = (const float*)d_in[16];

  // workspace arena (aliased)
  char* ws = (char*)d_ws;
  u16* wqT   = (u16*)(ws + 0x0000000);  // wq^T then wk^T contiguous -> [2048][1024]
  u16* wkT   = (u16*)(ws + 0x0200000);
  u16* wvT   = (u16*)(ws + 0x0400000);
  u16* wapT  = (u16*)(ws + 0x0600000);
  u16* woutT = (u16*)(ws + 0x0800000);  // padded to [1024][1024]
  u16* w1T   = (u16*)(ws + 0x0A00000);
  u16* w2T   = (u16*)(ws + 0x1200000);
  u16* xn    = (u16*)(ws + 0x1A00000);  // later reused as xn2
  u16* valb  = (u16*)(ws + 0x2A00000);  // later reused as start of h
  u16* qkb   = (u16*)(ws + 0x3A00000);  // fused [8192][2048] bf16 (32 MB)
  u16* vT    = (u16*)(ws + 0x5A00000);  // f16
  u16* ob    = (u16*)(ws + 0x6A00000);  // later reused as x2b
  u16* x1b   = (u16*)(ws + 0x7A00000);  // bf16 residual stream (16 MB)
  u16* logb  = (u16*)(ws + 0x8A00000);  // bf16 logits [8192][1000]
  u16* hb    = valb;
  u16* xn2   = xn;
  u16* x2b   = ob;

  dim3 tb(32, 8);
  transpose_w5<<<dim3(32, 32, 5), tb, 0, stream>>>(wq, wk, wv, w_ap, w_out,
                                                   wqT, wkT, wvT, wapT, woutT);
  transpose_w<<<dim3(32, 128), tb, 0, stream>>>(w1, w1T, 1024, 4096, 4096);
  transpose_w<<<dim3(128, 32), tb, 0, stream>>>(w2, w2T, 4096, 1024, 1024);

  convert_bf16<<<2048, 256, 0, stream>>>(value, valb, 2097152);
  layernorm_k<<<8192, 256, 0, stream>>>(x, g1, be1, xn);

  // fused q|k projection (q cols scaled 1/32*log2e in epilogue)
  gemm_8ph<EPI_QK, 256><<<dim3(8, 32),  512, 0, stream>>>(xn,   wqT, qkb, nullptr, nullptr, 8192, 2048, 1024, 1.0f);
  gemm_8ph<EPI_VT, 128><<<dim3(8, 32),  512, 0, stream>>>(valb, wvT, vT,  nullptr, nullptr, 8192, 1024, 1024, 1.0f);

  attn_flash<<<dim3(64, 16), 256, 0, stream>>>(qkb, vT, ob);

  gemm_8ph<EPI_RESID_X1, 128><<<dim3(8, 32),  512, 0, stream>>>(ob,  wapT, x1b, b_ap, x, 8192, 1024, 1024, 1.0f);
  layernorm_bf16<<<8192, 256, 0, stream>>>(x1b, g2, be2, xn2);
  gemm_8ph<EPI_GELU, 256>     <<<dim3(16, 32), 512, 0, stream>>>(xn2, w1T, hb, b1, nullptr, 8192, 4096, 1024, 1.0f);
  gemm_8ph<EPI_RESID_BF16, 128><<<dim3(8, 32), 512, 0, stream>>>(hb,  w2T, x2b, b2, (const float*)x1b, 8192, 1024, 4096, 1.0f);
  gemm_8ph<EPI_LOGITS, 128>   <<<dim3(8, 32),  512, 0, stream>>>(x2b, woutT, logb, b_out, nullptr, 8192, 1024, 1024, 1.0f);
  softmax_rows_b<<<8192, 256, 0, stream>>>(logb, (float*)d_out);
}

// Round 25
// 397.633 us; speedup vs baseline: 1.0399x; 1.0362x over previous
//
#include <hip/hip_runtime.h>
#include <math.h>

typedef unsigned short u16;
typedef unsigned int u32;
typedef __attribute__((ext_vector_type(4))) float f32x4;
typedef __attribute__((ext_vector_type(4))) int i32x4;
typedef __attribute__((ext_vector_type(8))) short short8;
typedef __attribute__((ext_vector_type(4))) unsigned short u16x4;
typedef __attribute__((ext_vector_type(4))) __fp16 f16x4;
typedef __attribute__((ext_vector_type(2))) __fp16 f16x2;

#define DEV __device__ __forceinline__

DEV u16 f2bf(float f) {
  unsigned u = __float_as_uint(f);
  u += 0x7FFFu + ((u >> 16) & 1u);
  return (u16)(u >> 16);
}

DEV float bf2f(u16 b) { return __uint_as_float(((u32)b) << 16); }

DEV float fexp2(float x) {  // v_exp_f32 is natively 2^x
  float r;
  asm("v_exp_f32 %0, %1" : "=v"(r) : "v"(x));
  return r;
}

DEV void gload_lds16(const void* g, void* l) {
  __builtin_amdgcn_global_load_lds((const __attribute__((address_space(1))) void*)g,
                                   (__attribute__((address_space(3))) void*)l, 16, 0, 0);
}

template<int N> DEV void waitv() {
  if constexpr (N == 4)      asm volatile("s_waitcnt vmcnt(4)" ::: "memory");
  else if constexpr (N == 3) asm volatile("s_waitcnt vmcnt(3)" ::: "memory");
  else if constexpr (N == 2) asm volatile("s_waitcnt vmcnt(2)" ::: "memory");
  else                       asm volatile("s_waitcnt vmcnt(0)" ::: "memory");
}

DEV void bar() {  // raw barrier, memory-clobber only (NO sched_barrier: m141)
  asm volatile("s_barrier" ::: "memory");
}

enum { EPI_QK = 0, EPI_VT = 1, EPI_RESID_X1 = 2, EPI_GELU = 3, EPI_RESID_BF16 = 4, EPI_LOGITS = 5 };

// ---------------- weight transpose: f32 [K][Nsrc] -> bf16 [Nout][K]
__global__ void transpose_w(const float* __restrict__ in, u16* __restrict__ out,
                            int K, int Nsrc, int Nout) {
  __shared__ float tile[32][33];
  int k0 = blockIdx.x * 32, n0 = blockIdx.y * 32;
  int tx = threadIdx.x, ty = threadIdx.y;
#pragma unroll
  for (int i = 0; i < 4; ++i) {
    int k = k0 + ty + i * 8, n = n0 + tx;
    tile[ty + i * 8][tx] = (n < Nsrc) ? in[(size_t)k * Nsrc + n] : 0.0f;
  }
  __syncthreads();
#pragma unroll
  for (int i = 0; i < 4; ++i) {
    int n = n0 + ty + i * 8, k = k0 + tx;
    out[(size_t)n * K + k] = f2bf(tile[tx][ty + i * 8]);
  }
}

// ---------------- batched 1024-row transposes (z selects src/dst; z==4: w_out, Nsrc=1000)
__global__ void transpose_w5(const float* __restrict__ s0, const float* __restrict__ s1,
                             const float* __restrict__ s2, const float* __restrict__ s3,
                             const float* __restrict__ s4,
                             u16* __restrict__ d0, u16* __restrict__ d1,
                             u16* __restrict__ d2, u16* __restrict__ d3,
                             u16* __restrict__ d4) {
  __shared__ float tile[32][33];
  const float* in; u16* out; int Nsrc = 1024;
  switch (blockIdx.z) {
    case 0: in = s0; out = d0; break;
    case 1: in = s1; out = d1; break;
    case 2: in = s2; out = d2; break;
    case 3: in = s3; out = d3; break;
    default: in = s4; out = d4; Nsrc = 1000; break;
  }
  int k0 = blockIdx.x * 32, n0 = blockIdx.y * 32;
  int tx = threadIdx.x, ty = threadIdx.y;
#pragma unroll
  for (int i = 0; i < 4; ++i) {
    int k = k0 + ty + i * 8, n = n0 + tx;
    tile[ty + i * 8][tx] = (n < Nsrc) ? in[(size_t)k * Nsrc + n] : 0.0f;
  }
  __syncthreads();
#pragma unroll
  for (int i = 0; i < 4; ++i) {
    int n = n0 + ty + i * 8, k = k0 + tx;
    out[(size_t)n * 1024 + k] = f2bf(tile[tx][ty + i * 8]);
  }
}

// ---------------- f32 -> bf16 elementwise (n4 = n/4 groups)
__global__ void convert_bf16(const float* __restrict__ in, u16* __restrict__ out, int n4) {
  int i = blockIdx.x * blockDim.x + threadIdx.x;
  int stride = gridDim.x * blockDim.x;
  for (int j = i; j < n4; j += stride) {
    f32x4 v = reinterpret_cast<const f32x4*>(in)[j];
    u16x4 o;
    o[0] = f2bf(v[0]); o[1] = f2bf(v[1]); o[2] = f2bf(v[2]); o[3] = f2bf(v[3]);
    reinterpret_cast<u16x4*>(out)[j] = o;
  }
}

// ---------------- block reduce helpers (256 threads = 4 waves)
DEV float blockReduceSum(float v) {
  __shared__ float red[4];
#pragma unroll
  for (int m = 32; m >= 1; m >>= 1) v += __shfl_xor(v, m);
  __syncthreads();
  if ((threadIdx.x & 63) == 0) red[threadIdx.x >> 6] = v;
  __syncthreads();
  return red[0] + red[1] + red[2] + red[3];
}

DEV float blockReduceMax(float v) {
  __shared__ float redm[4];
#pragma unroll
  for (int m = 32; m >= 1; m >>= 1) v = fmaxf(v, __shfl_xor(v, m));
  __syncthreads();
  if ((threadIdx.x & 63) == 0) redm[threadIdx.x >> 6] = v;
  __syncthreads();
  return fmaxf(fmaxf(redm[0], redm[1]), fmaxf(redm[2], redm[3]));
}

// ---------------- LayerNorm: f32 [rows][1024] -> bf16, row per block
__global__ __launch_bounds__(256)
void layernorm_k(const float* __restrict__ x, const float* __restrict__ g,
                 const float* __restrict__ b, u16* __restrict__ out) {
  int row = blockIdx.x, t = threadIdx.x;
  const float* xr = x + (size_t)row * 1024;
  f32x4 v = *reinterpret_cast<const f32x4*>(xr + t * 4);
  float mu = blockReduceSum(v[0] + v[1] + v[2] + v[3]) * (1.0f / 1024.0f);
  f32x4 d;
  d[0] = v[0] - mu; d[1] = v[1] - mu; d[2] = v[2] - mu; d[3] = v[3] - mu;
  float var = blockReduceSum(d[0]*d[0] + d[1]*d[1] + d[2]*d[2] + d[3]*d[3]) * (1.0f / 1024.0f);
  float rstd = rsqrtf(var + 1e-5f);
  u16x4 o;
#pragma unroll
  for (int i = 0; i < 4; ++i) o[i] = f2bf(d[i] * rstd * g[t * 4 + i] + b[t * 4 + i]);
  *reinterpret_cast<u16x4*>(out + (size_t)row * 1024 + t * 4) = o;
}

// ---------------- LayerNorm, bf16 input: [rows][1024] bf16 -> bf16
__global__ __launch_bounds__(256)
void layernorm_bf16(const u16* __restrict__ x, const float* __restrict__ g,
                    const float* __restrict__ b, u16* __restrict__ out) {
  int row = blockIdx.x, t = threadIdx.x;
  const u16* xr = x + (size_t)row * 1024;
  u16x4 raw = *reinterpret_cast<const u16x4*>(xr + t * 4);
  f32x4 v;
#pragma unroll
  for (int i = 0; i < 4; ++i) v[i] = bf2f(raw[i]);
  float mu = blockReduceSum(v[0] + v[1] + v[2] + v[3]) * (1.0f / 1024.0f);
  f32x4 d;
  d[0] = v[0] - mu; d[1] = v[1] - mu; d[2] = v[2] - mu; d[3] = v[3] - mu;
  float var = blockReduceSum(d[0]*d[0] + d[1]*d[1] + d[2]*d[2] + d[3]*d[3]) * (1.0f / 1024.0f);
  float rstd = rsqrtf(var + 1e-5f);
  u16x4 o;
#pragma unroll
  for (int i = 0; i < 4; ++i) o[i] = f2bf(d[i] * rstd * g[t * 4 + i] + b[t * 4 + i]);
  *reinterpret_cast<u16x4*>(out + (size_t)row * 1024 + t * 4) = o;
}

// ---------------- final row softmax: bf16 logits [rows][1000] -> f32 probs
__global__ __launch_bounds__(256)
void softmax_rows_b(const u16* __restrict__ in, float* __restrict__ outp) {
  int row = blockIdx.x, t = threadIdx.x;
  const u16* p = in + (size_t)row * 1000;
  float* q = outp + (size_t)row * 1000;
  float v[4];
  float mx = -INFINITY;
#pragma unroll
  for (int i = 0; i < 4; ++i) {
    int c = t + i * 256;
    v[i] = (c < 1000) ? bf2f(p[c]) : -INFINITY;
    mx = fmaxf(mx, v[i]);
  }
  mx = blockReduceMax(mx);
  float s = 0.f;
#pragma unroll
  for (int i = 0; i < 4; ++i) {
    int c = t + i * 256;
    v[i] = (c < 1000) ? __expf(v[i] - mx) : 0.f;
    s += v[i];
  }
  s = blockReduceSum(s);
  float inv = 1.0f / s;
#pragma unroll
  for (int i = 0; i < 4; ++i) {
    int c = t + i * 256;
    if (c < 1000) q[c] = v[i] * inv;
  }
}

// ---------------- pipelined bf16 MFMA GEMM, C = A @ Bt^T, XCD-swizzled.
// 512 thr = 8 waves (2M x 4N). BM=256/BN=256: 4 phases, 128KB LDS, 1 blk/CU.
// BM=256/BN=128: 2 phases, 96KB, 1 blk/CU. NEW BM=128/BN=128: 2 phases, 64KB
// -> 2 blocks/CU (16 waves): co-resident block covers vmcnt/barrier drains
// (the R19 attn occupancy mechanism applied to GEMM).
// Counted vmcnt (never 0 mid-loop except where nothing deeper in flight),
// raw s_barrier. Swizzle: slot ^= (row&7).
template<int EPI, int BN, int BM = 256>
__global__ __launch_bounds__(512)
void gemm_8ph(const u16* __restrict__ A, const u16* __restrict__ Bt,
              void* __restrict__ outp, const float* __restrict__ aux0,
              const float* __restrict__ aux1, int M, int N, int K, float scale) {
  constexpr int NJ = BN / 64;             // B-frags per wave (4 or 2)
  constexpr int AI = BM / 64;             // A-frags per wave per mh (4 or 2)
  __shared__ u16 As[2][BM * 64];
  __shared__ u16 Bs[2][BN * 64];

  const int t = threadIdx.x;
  const int lane = t & 63;
  const int w = t >> 6;
  const int wm = w >> 2, wn = w & 3;
  // XCD-aware chunked swizzle (T1): nwg % 8 == 0 for all our grids
  const int flat = blockIdx.y * gridDim.x + blockIdx.x;
  const int qch = (gridDim.x * gridDim.y) >> 3;
  const int nid = (flat & 7) * qch + (flat >> 3);
  const int bm = (nid / gridDim.x) * BM, bn = (nid % gridDim.x) * BN;
  const int l15 = lane & 15, lg = lane >> 4;
  const int nt = K >> 6;

  f32x4 acc[2 * AI][NJ] = {};
  short8 aR[AI][2], bR[2][2];

  auto stA = [&](int buf, int kt, int q) {
    int rl = q * 64 + (t >> 3), s0 = t & 7;
    gload_lds16(A + (size_t)(bm + rl) * K + kt * 64 + (s0 ^ (rl & 7)) * 8,
                &As[buf][q * 4096 + t * 8]);
  };
  auto stB = [&](int buf, int kt, int q) {
    int rl = q * 64 + (t >> 3), s0 = t & 7;
    gload_lds16(Bt + (size_t)(bn + rl) * K + kt * 64 + (s0 ^ (rl & 7)) * 8,
                &Bs[buf][q * 4096 + t * 8]);
  };
  auto rdA = [&](int buf, int mh) {
#pragma unroll
    for (int i2 = 0; i2 < AI; ++i2) {
      int rA = wm * (BM / 2) + mh * (BM / 4) + i2 * 16 + l15;
#pragma unroll
      for (int ks = 0; ks < 2; ++ks)
        aR[i2][ks] = *reinterpret_cast<const short8*>(
            &As[buf][rA * 64 + (((ks * 4 + lg) ^ (rA & 7)) * 8)]);
    }
  };
  auto rdB = [&](int buf, int nh) {
#pragma unroll
    for (int j2 = 0; j2 < 2; ++j2) {
      int rB = (BN == 256) ? (wn * 64 + nh * 32 + j2 * 16 + l15)
                           : (wn * 32 + j2 * 16 + l15);
#pragma unroll
      for (int ks = 0; ks < 2; ++ks)
        bR[j2][ks] = *reinterpret_cast<const short8*>(
            &Bs[buf][rB * 64 + (((ks * 4 + lg) ^ (rB & 7)) * 8)]);
    }
  };
  auto domfma = [&](int mh, int nh) {
    __builtin_amdgcn_s_setprio(1);
#pragma unroll
    for (int i2 = 0; i2 < AI; ++i2)
#pragma unroll
      for (int j2 = 0; j2 < 2; ++j2)
#pragma unroll
        for (int ks = 0; ks < 2; ++ks)
          acc[mh * AI + i2][nh * 2 + j2] = __builtin_amdgcn_mfma_f32_16x16x32_bf16(
              aR[i2][ks], bR[j2][ks], acc[mh * AI + i2][nh * 2 + j2], 0, 0, 0);
    __builtin_amdgcn_s_setprio(0);
  };

  // prologue: stage tile 0 in canonical (consumption) order
  if constexpr (BM == 256 && BN == 256) {
    stB(0, 0, 0); stB(0, 0, 1); stB(0, 0, 2); stB(0, 0, 3);
    stA(0, 0, 0); stA(0, 0, 2); stA(0, 0, 1); stA(0, 0, 3);
  } else if constexpr (BM == 256 && BN == 128) {
    stB(0, 0, 0); stB(0, 0, 1);
    stA(0, 0, 0); stA(0, 0, 2); stA(0, 0, 1); stA(0, 0, 3);
  } else {  // BM==128, BN==128
    stB(0, 0, 0); stB(0, 0, 1);
    stA(0, 0, 0); stA(0, 0, 1);
  }

#pragma unroll 1
  for (int tt = 0; tt < nt; ++tt) {
    const int buf = tt & 1, nb = buf ^ 1;
    const bool pf = (tt + 1 < nt);
    if constexpr (BM == 256 && BN == 256) {
      waitv<2>();
      bar();
      rdA(buf, 0); rdB(buf, 0);
      if (pf) { stB(nb, tt + 1, 0); stB(nb, tt + 1, 1); }
      domfma(0, 0);
      bar();
      rdB(buf, 1);
      if (pf) { stB(nb, tt + 1, 2); stB(nb, tt + 1, 3); }
      domfma(0, 1);
      if (pf) waitv<4>(); else waitv<0>();
      bar();
      rdA(buf, 1);
      if (pf) { stA(nb, tt + 1, 0); stA(nb, tt + 1, 2); }
      domfma(1, 1);
      bar();
      rdB(buf, 0);
      if (pf) { stA(nb, tt + 1, 1); stA(nb, tt + 1, 3); }
      domfma(1, 0);
    } else if constexpr (BM == 256 && BN == 128) {
      waitv<2>();
      bar();
      rdA(buf, 0); rdB(buf, 0);
      if (pf) { stB(nb, tt + 1, 0); stB(nb, tt + 1, 1); stA(nb, tt + 1, 0); }
      domfma(0, 0);
      if (pf) waitv<3>(); else waitv<0>();
      bar();
      rdA(buf, 1);
      if (pf) { stA(nb, tt + 1, 2); stA(nb, tt + 1, 1); stA(nb, tt + 1, 3); }
      domfma(1, 0);
    } else {  // BM==128, BN==128: wave mh-halves straddle both A chunks ->
      // P0 needs the whole tile; drain (nothing deeper in flight at P0).
      // Cross-block overlap (2 blocks/CU) provides the latency hiding.
      waitv<0>();
      bar();
      rdA(buf, 0); rdB(buf, 0);
      if (pf) { stB(nb, tt + 1, 0); stB(nb, tt + 1, 1); }
      domfma(0, 0);
      bar();                      // B(t+1) stays in flight (no wait here)
      rdA(buf, 1);
      if (pf) { stA(nb, tt + 1, 0); stA(nb, tt + 1, 1); }
      domfma(1, 0);
    }
  }

  // epilogue: C/D layout col=lane&15, row=(lane>>4)*4+reg
#pragma unroll
  for (int i = 0; i < 2 * AI; ++i)
#pragma unroll
    for (int j = 0; j < NJ; ++j)
#pragma unroll
      for (int r = 0; r < 4; ++r) {
        int row = bm + wm * (BM / 2) + i * 16 + lg * 4 + r;
        int col = bn + wn * (BN / 4) + j * 16 + l15;
        float v = acc[i][j][r];
        if constexpr (EPI == EPI_QK) {
          // q cols get SCALE*log2e folded (attn uses exp2 directly; R5-verified)
          float sc = (col < 1024) ? 0.03125f * 1.44269504088896f : 1.0f;
          ((u16*)outp)[(size_t)row * 2048 + col] = f2bf(v * sc);
        } else if constexpr (EPI == EPI_VT) {
          size_t idx = ((size_t)((row >> 11) * 16 + (col >> 6)) * 64 + (col & 63)) * 2048 + (row & 2047);
          __fp16 hv = (__fp16)v;
          ((u16*)outp)[idx] = *reinterpret_cast<u16*>(&hv);
        } else if constexpr (EPI == EPI_RESID_X1) {
          // v + bias + f32 residual -> bf16 residual stream
          ((u16*)outp)[(size_t)row * N + col] = f2bf(v + aux0[col] + aux1[(size_t)row * N + col]);
        } else if constexpr (EPI == EPI_GELU) {
          float tt2 = v + aux0[col];
          float u = tt2 * (0.7978845608f + 0.035677408f * tt2 * tt2);
          float e = fexp2(u * 2.8853900818f);
          float gl = tt2 * (1.0f - 1.0f / (1.0f + e));
          ((u16*)outp)[(size_t)row * N + col] = f2bf(gl);
        } else if constexpr (EPI == EPI_RESID_BF16) {
          // v + bias + bf16 residual (aux1 reinterpreted as u16) -> bf16
          float res = bf2f(((const u16*)aux1)[(size_t)row * N + col]);
          ((u16*)outp)[(size_t)row * N + col] = f2bf(v + aux0[col] + res);
        } else {  // EPI_LOGITS: bf16 logits (softmax reads bf16)
          if (col < 1000) ((u16*)outp)[(size_t)row * 1000 + col] = f2bf(v + aux0[col]);
        }
      }
  (void)scale; (void)aux0; (void)aux1; (void)M;
}

// ---------------- flash attention (R19-exact, measured best ~89us): KBLK=64
// (32KB LDS -> 4 blocks/CU), QBLK=128, 4 waves x 32 q-rows (2 q-groups/wave:
// each K b128 / V b64 LDS read feeds TWO MFMAs). Shuffle-based row-sums.
// Double-buffered prefetch; no-max softmax (q carries 1/32*log2e -> exp2);
// PV via 16x16x16 f16 MFMA (S^T frag = A-frag, zero shuffles).
// QK fused buffer [8192][2048]: q cols 0-1023, k cols 1024-2047.
// Vt [64 bh][64 d][2048 n] f16 -> O [8192][1024] bf16. grid (64 bh, 16 qblk).
__global__ __launch_bounds__(256, 4)
void attn_flash(const u16* __restrict__ QKb, const u16* __restrict__ Vt,
                u16* __restrict__ Ob) {
  __shared__ u16 Ks[2][64 * 64];     // bf16 [k=64][d=64], swizzled 16B slots
  __shared__ u16 Vs[2][64 * 64];     // f16  [d=64][k=64], swizzled 16B slots
  const int t = threadIdx.x;          // 0..255
  const int lane = t & 63, w = t >> 6;   // w in 0..3
  const int l15 = lane & 15, lg = lane >> 4;
  const int bh = blockIdx.x;
  const int b = bh >> 4, h = bh & 15;
  const int qrow0 = b * 2048 + blockIdx.y * 128 + w * 32;  // wave owns 32 q-rows

  short8 qf0[2], qf1[2];  // q-group 0: rows +l15; group 1: rows +16+l15
#pragma unroll
  for (int ks = 0; ks < 2; ++ks) {
    qf0[ks] = *reinterpret_cast<const short8*>(QKb + (size_t)(qrow0 + l15) * 2048 + h * 64 + ks * 32 + lg * 8);
    qf1[ks] = *reinterpret_cast<const short8*>(QKb + (size_t)(qrow0 + 16 + l15) * 2048 + h * 64 + ks * 32 + lg * 8);
  }

  f32x4 oacc0[4] = {}, oacc1[4] = {};
  float lp0 = 0.f, lp1 = 0.f;

  // both K and V rows are 64 elems = 8 x 16B slots; same staging algebra
  const int sg8 = ((t & 7) ^ ((t >> 3) & 7)) * 8;   // pre-swizzled src slot
  const int tk8 = t * 8;

  // 256 thr x 2 chunks = 512 chunks of 16B per tile (K and V each; 8KB each).
  auto STAGE = [&](int buf, int tt) {
    int kt = tt * 64;
#pragma unroll
    for (int p = 0; p < 2; ++p) {
      int rK = p * 32 + (t >> 3);
      gload_lds16(QKb + (size_t)(b * 2048 + kt + rK) * 2048 + 1024 + h * 64 + sg8, &Ks[buf][p * 2048 + tk8]);
      int rV = p * 32 + (t >> 3);
      gload_lds16(Vt + ((size_t)bh * 64 + rV) * 2048 + kt + sg8, &Vs[buf][p * 2048 + tk8]);
    }
  };

  auto COMPUTE = [&](int buf) {
    // S^T = K Q^T: lane holds q=l15 (per group), k=cb*16+lg*4+r, cb in 0..3
    f32x4 s0[4], s1[4];
    __builtin_amdgcn_s_setprio(1);
#pragma unroll
    for (int cb = 0; cb < 4; ++cb) {
      s0[cb] = f32x4{0.f, 0.f, 0.f, 0.f};
      s1[cb] = f32x4{0.f, 0.f, 0.f, 0.f};
      int rK = cb * 16 + l15;
#pragma unroll
      for (int ks = 0; ks < 2; ++ks) {
        int sk = (lg + ks * 4) ^ (rK & 7);
        short8 kf = *reinterpret_cast<const short8*>(&Ks[buf][rK * 64 + sk * 8]);
        s0[cb] = __builtin_amdgcn_mfma_f32_16x16x32_bf16(kf, qf0[ks], s0[cb], 0, 0, 0);
        s1[cb] = __builtin_amdgcn_mfma_f32_16x16x32_bf16(kf, qf1[ks], s1[cb], 0, 0, 0);
      }
    }
    __builtin_amdgcn_s_setprio(0);

    const char* vbase = (const char*)&Vs[buf][0];
#pragma unroll
    for (int cb = 0; cb < 4; ++cb) {
      float a0 = fexp2(s0[cb][0]), a1 = fexp2(s0[cb][1]);
      float a2 = fexp2(s0[cb][2]), a3 = fexp2(s0[cb][3]);
      lp0 += (a0 + a1) + (a2 + a3);
      f16x2 plo0 = __builtin_amdgcn_cvt_pkrtz(a0, a1);
      f16x2 phi0 = __builtin_amdgcn_cvt_pkrtz(a2, a3);
      f16x4 pf0;
      pf0[0] = plo0[0]; pf0[1] = plo0[1]; pf0[2] = phi0[0]; pf0[3] = phi0[1];
      float c0 = fexp2(s1[cb][0]), c1 = fexp2(s1[cb][1]);
      float c2 = fexp2(s1[cb][2]), c3 = fexp2(s1[cb][3]);
      lp1 += (c0 + c1) + (c2 + c3);
      f16x2 plo1 = __builtin_amdgcn_cvt_pkrtz(c0, c1);
      f16x2 phi1 = __builtin_amdgcn_cvt_pkrtz(c2, c3);
      f16x4 pf1;
      pf1[0] = plo1[0]; pf1[1] = plo1[1]; pf1[2] = phi1[0]; pf1[3] = phi1[1];
      // P fragment already in x16 A-layout: lane holds P[q=l15][k=16cb+4lg+j]
      __builtin_amdgcn_s_setprio(1);
#pragma unroll
      for (int db = 0; db < 4; ++db) {
        int d = db * 16 + l15;
        // V^T[d][k] b64: row stride 128B (8 slots); logical slot 2cb+(lg>>1)
        int boff = d * 128 + ((((2 * cb + (lg >> 1)) ^ (d & 7)) << 4) | ((lg & 1) << 3));
        f16x4 vf = *reinterpret_cast<const f16x4*>(vbase + boff);
        oacc0[db] = __builtin_amdgcn_mfma_f32_16x16x16f16(pf0, vf, oacc0[db], 0, 0, 0);
        oacc1[db] = __builtin_amdgcn_mfma_f32_16x16x16f16(pf1, vf, oacc1[db], 0, 0, 0);
      }
      __builtin_amdgcn_s_setprio(0);
    }
  };

  STAGE(0, 0);
  __syncthreads();  // drains vmcnt(0): tile 0 staged
#pragma unroll 1
  for (int i = 0; i < 16; ++i) {
    STAGE(1, 2 * i + 1);   // prefetch overlaps compute below
    COMPUTE(0);
    __syncthreads();       // drains prefetch; buf1 ready, buf0 free
    if (i < 15) STAGE(0, 2 * i + 2);
    COMPUTE(1);
    __syncthreads();
  }

  // row-sum reduce + O write, group 0 (rows qrow0 + lg*4+r)
  lp0 += __shfl_xor(lp0, 16);
  lp0 += __shfl_xor(lp0, 32);
  float inv0 = 1.0f / lp0;
  float invr0[4];
#pragma unroll
  for (int r = 0; r < 4; ++r) invr0[r] = __shfl(inv0, lg * 4 + r);
#pragma unroll
  for (int db = 0; db < 4; ++db)
#pragma unroll
    for (int r = 0; r < 4; ++r) {
      int row = qrow0 + lg * 4 + r;
      int col = h * 64 + db * 16 + l15;
      Ob[(size_t)row * 1024 + col] = f2bf(oacc0[db][r] * invr0[r]);
    }
  // group 1 (rows qrow0 + 16 + lg*4+r)
  lp1 += __shfl_xor(lp1, 16);
  lp1 += __shfl_xor(lp1, 32);
  float inv1 = 1.0f / lp1;
  float invr1[4];
#pragma unroll
  for (int r = 0; r < 4; ++r) invr1[r] = __shfl(inv1, lg * 4 + r);
#pragma unroll
  for (int db = 0; db < 4; ++db)
#pragma unroll
    for (int r = 0; r < 4; ++r) {
      int row = qrow0 + 16 + lg * 4 + r;
      int col = h * 64 + db * 16 + l15;
      Ob[(size_t)row * 1024 + col] = f2bf(oacc1[db][r] * invr1[r]);
    }
}

extern "C" void kernel_launch(void* const* d_in, const int* in_sizes, int n_in,
                              void* d_out, int out_size, void* d_ws, size_t ws_size,
                              hipStream_t stream) {
  (void)in_sizes; (void)n_in; (void)out_size; (void)ws_size;
  const float* x     = (const float*)d_in[0];
  const float* value = (const float*)d_in[1];
  const float* wq    = (const float*)d_in[2];
  const float* wk    = (const float*)d_in[3];
  const float* wv    = (const float*)d_in[4];
  const float* w_ap  = (const float*)d_in[5];
  const float* b_ap  = (const float*)d_in[6];
  const float* g1    = (const float*)d_in[7];
  const float* be1   = (const float*)d_in[8];
  const float* g2    = (const float*)d_in[9];
  const float* be2   = (const float*)d_in[10];
  const float* w1    = (const float*)d_in[11];
  const float* b1    = (const float*)d_in[12];
  const float* w2    = (const float*)d_in[13];
  const float* b2    = (const float*)d_in[14];
  const float* w_out = (const float*)d_in[15];
  const float* b_out = (const float*)d_in[16];

  // workspace arena (aliased)
  char* ws = (char*)d_ws;
  u16* wqT   = (u16*)(ws + 0x0000000);  // wq^T then wk^T contiguous -> [2048][1024]
  u16* wkT   = (u16*)(ws + 0x0200000);
  u16* wvT   = (u16*)(ws + 0x0400000);
  u16* wapT  = (u16*)(ws + 0x0600000);
  u16* woutT = (u16*)(ws + 0x0800000);  // padded to [1024][1024]
  u16* w1T   = (u16*)(ws + 0x0A00000);
  u16* w2T   = (u16*)(ws + 0x1200000);
  u16* xn    = (u16*)(ws + 0x1A00000);  // later reused as xn2
  u16* valb  = (u16*)(ws + 0x2A00000);  // later reused as start of h
  u16* qkb   = (u16*)(ws + 0x3A00000);  // fused [8192][2048] bf16 (32 MB)
  u16* vT    = (u16*)(ws + 0x5A00000);  // f16
  u16* ob    = (u16*)(ws + 0x6A00000);  // later reused as x2b
  u16* x1b   = (u16*)(ws + 0x7A00000);  // bf16 residual stream (16 MB)
  u16* logb  = (u16*)(ws + 0x8A00000);  // bf16 logits [8192][1000]
  u16* hb    = valb;
  u16* xn2   = xn;
  u16* x2b   = ob;

  dim3 tb(32, 8);
  transpose_w5<<<dim3(32, 32, 5), tb, 0, stream>>>(wq, wk, wv, w_ap, w_out,
                                                   wqT, wkT, wvT, wapT, woutT);
  transpose_w<<<dim3(32, 128), tb, 0, stream>>>(w1, w1T, 1024, 4096, 4096);
  transpose_w<<<dim3(128, 32), tb, 0, stream>>>(w2, w2T, 4096, 1024, 1024);

  convert_bf16<<<2048, 256, 0, stream>>>(value, valb, 2097152);
  layernorm_k<<<8192, 256, 0, stream>>>(x, g1, be1, xn);

  // fused q|k projection (q cols scaled 1/32*log2e in epilogue)
  gemm_8ph<EPI_QK, 256><<<dim3(8, 32),  512, 0, stream>>>(xn,   wqT, qkb, nullptr, nullptr, 8192, 2048, 1024, 1.0f);
  gemm_8ph<EPI_VT, 128, 128><<<dim3(8, 64), 512, 0, stream>>>(valb, wvT, vT, nullptr, nullptr, 8192, 1024, 1024, 1.0f);

  attn_flash<<<dim3(64, 16), 256, 0, stream>>>(qkb, vT, ob);

  gemm_8ph<EPI_RESID_X1, 128, 128><<<dim3(8, 64), 512, 0, stream>>>(ob, wapT, x1b, b_ap, x, 8192, 1024, 1024, 1.0f);
  layernorm_bf16<<<8192, 256, 0, stream>>>(x1b, g2, be2, xn2);
  gemm_8ph<EPI_GELU, 256>     <<<dim3(16, 32), 512, 0, stream>>>(xn2, w1T, hb, b1, nullptr, 8192, 4096, 1024, 1.0f);
  gemm_8ph<EPI_RESID_BF16, 128, 128><<<dim3(8, 64), 512, 0, stream>>>(hb, w2T, x2b, b2, (const float*)x1b, 8192, 1024, 4096, 1.0f);
  gemm_8ph<EPI_LOGITS, 128, 128><<<dim3(8, 64), 512, 0, stream>>>(x2b, woutT, logb, b_out, nullptr, 8192, 1024, 1024, 1.0f);
  softmax_rows_b<<<8192, 256, 0, stream>>>(logb, (float*)d_out);
}